// Round 3
// baseline (4379.354 us; speedup 1.0000x reference)
//
#include <hip/hip_runtime.h>
#include <cstdint>

typedef unsigned long long u64;

#define B_ 8
#define S_ 128
#define T_ 24
#define E_ 512
#define H_ 512
#define H3_ 1536
#define L_ 256
#define D_ 2048

__device__ __forceinline__ float fsig(float x) { return 1.0f / (1.0f + __expf(-x)); }
__device__ __forceinline__ float ftanh(float x) { return 1.0f - 2.0f / (1.0f + __expf(2.0f * x)); }
__device__ __forceinline__ float dot4(float4 a, float4 b) {
    return a.x * b.x + a.y * b.y + a.z * b.z + a.w * b.w;
}

// Tagged mailbox word: (tag<<32)|f32bits. Relaxed agent-scope atomics hit the
// LLC coherence point with no cache-maintenance ops; tag+payload share one
// atomic word so no fences/ordering are needed at all.
__device__ __forceinline__ u64 boxLoad(const u64* p) {
    return __hip_atomic_load((u64*)p, __ATOMIC_RELAXED, __HIP_MEMORY_SCOPE_AGENT);
}
__device__ __forceinline__ void boxStore(u64* p, unsigned tag, float v) {
    __hip_atomic_store(p, ((u64)tag << 32) | (u64)__float_as_uint(v),
                       __ATOMIC_RELAXED, __HIP_MEMORY_SCOPE_AGENT);
}

// ---------------------------------------------------------------------------
__global__ void k_init(const int* __restrict__ pre, const int* __restrict__ post,
                       const int* __restrict__ trg,
                       int* __restrict__ idxPre, int* __restrict__ idxPost,
                       int* __restrict__ idxTok, float* __restrict__ wEff,
                       float* __restrict__ c) {
    int tid = blockIdx.x * 256 + threadIdx.x;  // grid 8 x 256 = 2048
    if (tid < 1024) {
        int s = tid >> 3, b = tid & 7;
        idxPre[tid]  = pre[b * S_ + s];
        idxPost[tid] = post[b * S_ + s];
    }
    if (tid < T_ * B_) {
        int t = tid >> 3, b = tid & 7;
        idxTok[tid] = (t == 0) ? pre[b * S_ + (S_ - 1)] : trg[b * T_ + (t - 1)];
    }
    if (tid < 256) c[tid] = 0.f;
    wEff[tid] = 0.f;
}

// ---------------------------------------------------------------------------
// Tiled f32 GEMM: C[m][n] = sum_k A[m][k]*B[n][k] + bias[n]
// ---------------------------------------------------------------------------
__global__ __launch_bounds__(256) void k_gemm(
    const float* __restrict__ A, const int* __restrict__ Aidx, int lda,
    const float* __restrict__ Bm, int ldb,
    const float* __restrict__ bias, float* __restrict__ C,
    int N, int K) {
    __shared__ float As[16][68];
    __shared__ float Bs[16][68];
    const int m0 = blockIdx.x * 64, n0 = blockIdx.y * 64;
    const int tid = threadIdx.x;
    const int tm = tid >> 2;
    const int tk = (tid & 3) << 2;
    const int tx = tid & 15, ty = tid >> 4;
    const int am = m0 + tm;
    const float* Arow = A + (size_t)(Aidx ? Aidx[am] : am) * lda;
    const float* Brow = Bm + (size_t)(n0 + tm) * ldb;
    float acc[4][4] = {};
    for (int k0 = 0; k0 < K; k0 += 16) {
        float4 av = *(const float4*)(Arow + k0 + tk);
        float4 bv = *(const float4*)(Brow + k0 + tk);
        __syncthreads();
        As[tk][tm] = av.x; As[tk + 1][tm] = av.y; As[tk + 2][tm] = av.z; As[tk + 3][tm] = av.w;
        Bs[tk][tm] = bv.x; Bs[tk + 1][tm] = bv.y; Bs[tk + 2][tm] = bv.z; Bs[tk + 3][tm] = bv.w;
        __syncthreads();
#pragma unroll
        for (int k = 0; k < 16; ++k) {
            float4 a4 = *(const float4*)(&As[k][ty << 2]);
            float4 b4 = *(const float4*)(&Bs[k][tx << 2]);
            float ar[4] = {a4.x, a4.y, a4.z, a4.w};
            float br[4] = {b4.x, b4.y, b4.z, b4.w};
#pragma unroll
            for (int i = 0; i < 4; ++i)
#pragma unroll
                for (int j = 0; j < 4; ++j) acc[i][j] += ar[i] * br[j];
        }
    }
    float4 bb = bias ? *(const float4*)(bias + n0 + (tx << 2)) : make_float4(0.f, 0.f, 0.f, 0.f);
#pragma unroll
    for (int i = 0; i < 4; ++i) {
        int m = m0 + (ty << 2) + i;
        float4 o;
        o.x = acc[i][0] + bb.x; o.y = acc[i][1] + bb.y;
        o.z = acc[i][2] + bb.z; o.w = acc[i][3] + bb.w;
        *(float4*)(C + (size_t)m * N + n0 + (tx << 2)) = o;
    }
}

// ---------------------------------------------------------------------------
__global__ void k_weff(const float* __restrict__ fcW, const float* __restrict__ fcB,
                       const float* __restrict__ voW, const float* __restrict__ voB,
                       float* __restrict__ wEff, float* __restrict__ bEff) {
    __shared__ float red[256];
    int bx = blockIdx.x;
    if (bx < 128) {
        int cblk = bx & 7, q = bx >> 3;
        int col = cblk * 256 + threadIdx.x;
        int j0 = q * 128;
        float acc = 0.f;
        for (int j = j0; j < j0 + 128; ++j) acc += voW[j] * fcW[(size_t)j * D_ + col];
        atomicAdd(wEff + col, acc);
    } else {
        float p = 0.f;
        for (int j = threadIdx.x; j < D_; j += 256) p += voW[j] * fcB[j];
        red[threadIdx.x] = p;
        __syncthreads();
        for (int s = 128; s > 0; s >>= 1) {
            if (threadIdx.x < s) red[threadIdx.x] += red[threadIdx.x + s];
            __syncthreads();
        }
        if (threadIdx.x == 0) bEff[0] = red[0] + voB[0];
    }
}

// ---------------------------------------------------------------------------
// Encoder scan: 64 WGs (32 per GRU) x 256 thr. Thread = (col jj, batch b,
// k-half kh); computes all 3 gate rows of its column -> local h2. h exchanged
// via tagged mailbox (double-buffered by step parity), no barriers.
// ---------------------------------------------------------------------------
__global__ __launch_bounds__(256) void k_encoder(
    const float* __restrict__ giPre, const float* __restrict__ giPost,
    const float* __restrict__ WhhPre, const float* __restrict__ WhhPost,
    const float* __restrict__ bhhPre, const float* __restrict__ bhhPost,
    float* __restrict__ encOut, u64* __restrict__ hboxPre, u64* __restrict__ hboxPost) {
    const int g = blockIdx.x >> 5;
    const int c = blockIdx.x & 31;
    const int j0 = c << 4;
    const float* gi = g ? giPost : giPre;
    const float* Whh = g ? WhhPost : WhhPre;
    const float* bhh = g ? bhhPost : bhhPre;
    u64* hbox = g ? hboxPost : hboxPre;

    const int tid = threadIdx.x;
    const int jj = tid & 15;
    const int b = (tid >> 4) & 7;
    const int kh = tid >> 7;  // k-half 0/1
    const int j = j0 + jj;
    const int lane128 = tid & 127;

    __shared__ float hS[8 * 520];   // pad 520: batches land on distinct banks
    __shared__ float redE[384];     // kh=1 partials: 3 gates x 128

    const float4* wr = (const float4*)(Whh + (size_t)j * 512) + (kh << 6);
    const float4* wz = (const float4*)(Whh + (size_t)(512 + j) * 512) + (kh << 6);
    const float4* wn = (const float4*)(Whh + (size_t)(1024 + j) * 512) + (kh << 6);
    const float br_ = bhh[j], bz_ = bhh[512 + j], bn_ = bhh[1024 + j];

    for (int t = 0; t < S_; ++t) {
        if (t == 0) {
            for (int i = tid; i < 8 * 520; i += 256) hS[i] = 0.f;
        } else {
            const u64* box = hbox + (size_t)((t & 1) ^ 1) * 4096;
            u64 v[16];
#pragma unroll
            for (int q = 0; q < 16; ++q) v[q] = boxLoad(box + q * 256 + tid);
#pragma unroll
            for (int q = 0; q < 16; ++q) {
                while ((unsigned)(v[q] >> 32) != (unsigned)t)
                    v[q] = boxLoad(box + q * 256 + tid);
                int i = q * 256 + tid;  // i = b*512 + k
                hS[(i >> 9) * 520 + (i & 511)] = __uint_as_float((unsigned)v[q]);
            }
        }
        __syncthreads();
        const float4* h4 = (const float4*)(hS + b * 520) + (kh << 6);
        float ar = 0.f, az = 0.f, an = 0.f;
#pragma unroll 8
        for (int k = 0; k < 64; ++k) {
            float4 hv = h4[k];
            ar += dot4(wr[k], hv);
            az += dot4(wz[k], hv);
            an += dot4(wn[k], hv);
        }
        if (kh) {
            redE[lane128] = ar; redE[128 + lane128] = az; redE[256 + lane128] = an;
        }
        __syncthreads();
        if (!kh) {
            ar += redE[lane128] + br_;
            az += redE[128 + lane128] + bz_;
            an += redE[256 + lane128] + bn_;
            size_t gbase = ((size_t)t * 8 + b) * H3_;
            float r = fsig(gi[gbase + j] + ar);
            float z = fsig(gi[gbase + 512 + j] + az);
            float n = ftanh(gi[gbase + 1024 + j] + r * an);
            float h2 = (1.f - z) * n + z * hS[b * 520 + j];
            encOut[(((size_t)(b << 8) + (g << 7) + t) << 9) + j] = h2;
            boxStore(hbox + (size_t)(t & 1) * 4096 + (b << 9) + j, t + 1, h2);
        }
        __syncthreads();
    }
}

// ---------------------------------------------------------------------------
__global__ void k_fcenc(const float* __restrict__ encOut, const float* __restrict__ W,
                        const float* __restrict__ bias, float* __restrict__ h) {
    int o = blockIdx.x * 256 + threadIdx.x;  // grid 16 -> 4096
    int b = o >> 9, j = o & 511;
    const float4* w4 = (const float4*)(W + (size_t)j * 1024);
    const float4* pre4 = (const float4*)(encOut + (((size_t)(b << 8) + 127) << 9));
    const float4* post4 = (const float4*)(encOut + (((size_t)(b << 8) + 255) << 9));
    float acc = bias[j];
    for (int k = 0; k < 128; ++k) acc += dot4(w4[k], pre4[k]);
    for (int k = 0; k < 128; ++k) acc += dot4(w4[128 + k], post4[k]);
    h[o] = ftanh(acc);
}

// enc_dot[b*256+l] = enc_out[b,l,:] . w_eff[0:512]
__global__ void k_encdot(const float* __restrict__ encOut, const float* __restrict__ wEff,
                         float* __restrict__ encDot) {
    int wid = threadIdx.x >> 6, lane = threadIdx.x & 63;
    int gw = blockIdx.x * 4 + wid;  // grid 32 -> 128 waves
    for (int o = gw; o < 2048; o += 128) {
        const float* row = encOut + ((size_t)o << 9);
        float s = 0.f;
        for (int k = lane; k < 512; k += 64) s += row[k] * wEff[k];
        for (int off = 32; off; off >>= 1) s += __shfl_down(s, off);
        if (lane == 0) encDot[o] = s;
    }
}

// eDot4[t*8+b] = emb[tok[t,b]] . w_eff[1536:2048]
__global__ void k_edot4(const float* __restrict__ emb, const int* __restrict__ idxTok,
                        const float* __restrict__ wEff, float* __restrict__ eDot4) {
    int o = blockIdx.x;  // grid 192, block 64
    int lane = threadIdx.x;
    const float* row = emb + (size_t)idxTok[o] * E_;
    const float* w = wEff + 1536;
    float s = 0.f;
    for (int k = lane; k < 512; k += 64) s += row[k] * w[k];
    for (int off = 32; off; off >>= 1) s += __shfl_down(s, off);
    if (lane == 0) eDot4[o] = s;
}

// ---------------------------------------------------------------------------
// Decoder scan: 128 WGs x 128 thr, WG = (batch b, slice s). 4 tagged-mailbox
// exchanges per step (h, hp, scores, weighted); no barriers, no fences.
// ---------------------------------------------------------------------------
__global__ __launch_bounds__(128) void k_decoder(
    const float* __restrict__ encOut, const float* __restrict__ encProj,
    const float* __restrict__ attnW, const float* __restrict__ attnV,
    const float* __restrict__ WihDec, const float* __restrict__ WhhDec,
    const float* __restrict__ bhhDec, const float* __restrict__ giE,
    const float* __restrict__ wEff, const float* __restrict__ h0,
    u64* __restrict__ hpM, u64* __restrict__ scM, u64* __restrict__ wM,
    u64* __restrict__ hM, float* __restrict__ c) {
    const int tid = threadIdx.x;
    const int b = blockIdx.x >> 4, s = blockIdx.x & 15;

    __shared__ float hB[512];
    __shared__ float hpS[512];
    __shared__ float wSS[512];
    __shared__ float scS[256];
    __shared__ float aS[256];
    __shared__ float gh2S[96];
    __shared__ float gi2S[96];
    __shared__ float red[32][5];
    __shared__ float red2[16][9];
    __shared__ float red3[32][5];
    __shared__ float redS[128];

    for (int t = 0; t < T_; ++t) {
        // ---- A: obtain h; hp slice -> publish; gh2 slice -> LDS ----
        if (t == 0) {
#pragma unroll
            for (int q = 0; q < 4; ++q) hB[q * 128 + tid] = h0[(b << 9) + q * 128 + tid];
        } else {
            const u64* box = hM + (size_t)((t & 1) ^ 1) * 4096 + (b << 9);
            u64 v[4];
#pragma unroll
            for (int q = 0; q < 4; ++q) v[q] = boxLoad(box + q * 128 + tid);
#pragma unroll
            for (int q = 0; q < 4; ++q) {
                while ((unsigned)(v[q] >> 32) != (unsigned)t)
                    v[q] = boxLoad(box + q * 128 + tid);
                hB[q * 128 + tid] = __uint_as_float((unsigned)v[q]);
            }
        }
        __syncthreads();
        {
            int r = tid & 31, q = tid >> 5;
            const float4* w4 = (const float4*)(attnW + (size_t)(s * 32 + r) * 1024 + q * 128);
            const float4* h4 = (const float4*)(hB + q * 128);
            float acc = 0.f;
#pragma unroll
            for (int k = 0; k < 32; ++k) acc += dot4(w4[k], h4[k]);
            red[r][q] = acc;
        }
        __syncthreads();
        if (tid < 32) {
            float a = red[tid][0] + red[tid][1] + red[tid][2] + red[tid][3];
            boxStore(hpM + (size_t)(t & 1) * 4096 + (b << 9) + s * 32 + tid, t + 1, a);
        }
        if (tid < 96) {
            int gate = tid >> 5, jjj = tid & 31;
            int n = gate * 512 + s * 32 + jjj;
            const float4* w4 = (const float4*)(WhhDec + (size_t)n * 512);
            const float4* h4 = (const float4*)hB;
            float acc = bhhDec[n];
#pragma unroll 4
            for (int k = 0; k < 128; ++k) acc += dot4(w4[k], h4[k]);
            gh2S[tid] = acc;
        }
        // ---- B: obtain hp; score rows -> publish ----
        {
            const u64* box = hpM + (size_t)(t & 1) * 4096 + (b << 9);
            u64 v[4];
#pragma unroll
            for (int q = 0; q < 4; ++q) v[q] = boxLoad(box + q * 128 + tid);
#pragma unroll
            for (int q = 0; q < 4; ++q) {
                while ((unsigned)(v[q] >> 32) != (unsigned)(t + 1))
                    v[q] = boxLoad(box + q * 128 + tid);
                hpS[q * 128 + tid] = __uint_as_float((unsigned)v[q]);
            }
        }
        __syncthreads();
        {
            int r = tid & 15, q = tid >> 4;  // l = s*16+r, k in [q*64,..)
            int l = s * 16 + r;
            const float* ep = encProj + (((size_t)(b << 8) + l) << 9) + q * 64;
            const float* hp = hpS + q * 64;
            const float* av = attnV + q * 64;
            float acc = 0.f;
#pragma unroll 8
            for (int k = 0; k < 64; ++k) acc += av[k] * ftanh(ep[k] + hp[k]);
            red2[r][q] = acc;
        }
        __syncthreads();
        if (tid < 16) {
            float a = 0.f;
#pragma unroll
            for (int q = 0; q < 8; ++q) a += red2[tid][q];
            boxStore(scM + (size_t)(t & 1) * 2048 + (b << 8) + s * 16 + tid, t + 1, a);
        }
        // ---- C: obtain scores; softmax; weighted slice -> publish ----
        {
            const u64* box = scM + (size_t)(t & 1) * 2048 + (b << 8);
            u64 v[2];
#pragma unroll
            for (int q = 0; q < 2; ++q) v[q] = boxLoad(box + q * 128 + tid);
#pragma unroll
            for (int q = 0; q < 2; ++q) {
                while ((unsigned)(v[q] >> 32) != (unsigned)(t + 1))
                    v[q] = boxLoad(box + q * 128 + tid);
                scS[q * 128 + tid] = __uint_as_float((unsigned)v[q]);
            }
        }
        __syncthreads();
        {
            float s0 = scS[tid], s1 = scS[128 + tid];
            redS[tid] = fmaxf(s0, s1);
            __syncthreads();
            for (int st = 64; st > 0; st >>= 1) {
                if (tid < st) redS[tid] = fmaxf(redS[tid], redS[tid + st]);
                __syncthreads();
            }
            float mx = redS[0];
            __syncthreads();
            float e0 = __expf(s0 - mx), e1 = __expf(s1 - mx);
            redS[tid] = e0 + e1;
            __syncthreads();
            for (int st = 64; st > 0; st >>= 1) {
                if (tid < st) redS[tid] += redS[tid + st];
                __syncthreads();
            }
            float inv = 1.f / redS[0];
            aS[tid] = e0 * inv;
            aS[128 + tid] = e1 * inv;
        }
        __syncthreads();
        {
            int jjj = tid & 31, p = tid >> 5;
            int hc = s * 32 + jjj;
            float acc = 0.f;
            for (int l = p * 64; l < p * 64 + 64; ++l)
                acc += aS[l] * encOut[(((size_t)(b << 8) + l) << 9) + hc];
            red3[jjj][p] = acc;
        }
        __syncthreads();
        if (tid < 32) {
            float a = red3[tid][0] + red3[tid][1] + red3[tid][2] + red3[tid][3];
            boxStore(wM + (size_t)(t & 1) * 4096 + (b << 9) + s * 32 + tid, t + 1, a);
        }
        // ---- D: obtain weighted; gi2 slice; GRU update -> publish h ----
        {
            const u64* box = wM + (size_t)(t & 1) * 4096 + (b << 9);
            u64 v[4];
#pragma unroll
            for (int q = 0; q < 4; ++q) v[q] = boxLoad(box + q * 128 + tid);
#pragma unroll
            for (int q = 0; q < 4; ++q) {
                while ((unsigned)(v[q] >> 32) != (unsigned)(t + 1))
                    v[q] = boxLoad(box + q * 128 + tid);
                wSS[q * 128 + tid] = __uint_as_float((unsigned)v[q]);
            }
        }
        __syncthreads();
        if (tid < 96) {
            int gate = tid >> 5, jjj = tid & 31;
            int n = gate * 512 + s * 32 + jjj;
            const float4* w4 = (const float4*)(WihDec + (size_t)n * 1024 + 512);
            const float4* x4 = (const float4*)wSS;
            float acc = giE[((size_t)(t << 3) + b) * H3_ + n];
#pragma unroll 4
            for (int k = 0; k < 128; ++k) acc += dot4(w4[k], x4[k]);
            gi2S[tid] = acc;
        }
        __syncthreads();
        if (tid < 32) {
            int j = s * 32 + tid;
            float r = fsig(gi2S[tid] + gh2S[tid]);
            float z = fsig(gi2S[32 + tid] + gh2S[32 + tid]);
            float nn = ftanh(gi2S[64 + tid] + r * gh2S[64 + tid]);
            float h2 = (1.f - z) * nn + z * hB[j];
            boxStore(hM + (size_t)(t & 1) * 4096 + (b << 9) + j, t + 1, h2);
            float pc = h2 * wEff[1024 + j] + wSS[j] * wEff[512 + j];
#pragma unroll
            for (int off = 16; off; off >>= 1) pc += __shfl_down(pc, off);
            if (tid == 0) atomicAdd(c + b * T_ + t, pc);
        }
        __syncthreads();
    }
}

// out = enc_dot[b,l] + c[b,t] + bEff + eDot4[t,b]
__global__ void k_final(const float* __restrict__ encDot, const float* __restrict__ c,
                        const float* __restrict__ bEff, const float* __restrict__ eDot4,
                        float* __restrict__ out) {
    int idx = blockIdx.x * 256 + threadIdx.x;  // grid 192 -> 49152
    const int half = B_ * T_ * S_;
    int w = idx < half ? idx : idx - half;
    int b = w / (T_ * S_);
    int r = w % (T_ * S_);
    int t = r / S_, sidx = r % S_;
    int l = (idx < half) ? sidx : (S_ + sidx);
    out[idx] = encDot[b * L_ + l] + c[b * T_ + t] + bEff[0] + eDot4[t * 8 + b];
}

// ---------------------------------------------------------------------------
extern "C" void kernel_launch(void* const* d_in, const int* in_sizes, int n_in,
                              void* d_out, int out_size, void* d_ws, size_t ws_size,
                              hipStream_t stream) {
    const int* pre = (const int*)d_in[0];
    const int* post = (const int*)d_in[1];
    const int* trg = (const int*)d_in[2];
    const float* emb = (const float*)d_in[3];
    const float* WihPre = (const float*)d_in[4];
    const float* WhhPre = (const float*)d_in[5];
    const float* bihPre = (const float*)d_in[6];
    const float* bhhPre = (const float*)d_in[7];
    const float* WihPost = (const float*)d_in[8];
    const float* WhhPost = (const float*)d_in[9];
    const float* bihPost = (const float*)d_in[10];
    const float* bhhPost = (const float*)d_in[11];
    const float* fcEncW = (const float*)d_in[12];
    const float* fcEncB = (const float*)d_in[13];
    const float* attnW = (const float*)d_in[14];
    const float* attnB = (const float*)d_in[15];
    const float* attnV = (const float*)d_in[16];
    const float* WihDec = (const float*)d_in[17];
    const float* WhhDec = (const float*)d_in[18];
    const float* bihDec = (const float*)d_in[19];
    const float* bhhDec = (const float*)d_in[20];
    const float* fcHidW = (const float*)d_in[21];
    const float* fcHidB = (const float*)d_in[22];
    const float* fcOutW = (const float*)d_in[23];
    const float* fcOutB = (const float*)d_in[24];
    float* outp = (float*)d_out;

    float* base = (float*)d_ws;
    size_t off = 0;
    auto alloc = [&](size_t n) {
        float* p = base + off;
        off += (n + 63) & ~(size_t)63;
        return p;
    };
    float* giPre = alloc(1024 * 1536);
    float* giPost = alloc(1024 * 1536);
    float* giE = alloc(192 * 1536);
    float* encOut = alloc(8 * 256 * 512);
    float* encProj = alloc(8 * 256 * 512);
    float* wEff = alloc(2048);
    float* bEff = alloc(64);
    float* encDot = alloc(2048);
    float* eDot4 = alloc(256);
    float* hBuf = alloc(4096);
    float* cBuf = alloc(256);
    u64* hboxPre = (u64*)alloc(2 * 4096 * 2);
    u64* hboxPost = (u64*)alloc(2 * 4096 * 2);
    u64* hpM = (u64*)alloc(2 * 4096 * 2);
    u64* scM = (u64*)alloc(2 * 2048 * 2);
    u64* wM = (u64*)alloc(2 * 4096 * 2);
    u64* hM = (u64*)alloc(2 * 4096 * 2);
    int* idxPre = (int*)alloc(1024);
    int* idxPost = (int*)alloc(1024);
    int* idxTok = (int*)alloc(256);

    k_init<<<8, 256, 0, stream>>>(pre, post, trg, idxPre, idxPost, idxTok, wEff, cBuf);
    k_weff<<<129, 256, 0, stream>>>(fcHidW, fcHidB, fcOutW, fcOutB, wEff, bEff);
    k_gemm<<<dim3(16, 24), 256, 0, stream>>>(emb, idxPre, 512, WihPre, 512, bihPre, giPre, 1536, 512);
    k_gemm<<<dim3(16, 24), 256, 0, stream>>>(emb, idxPost, 512, WihPost, 512, bihPost, giPost, 1536, 512);
    k_gemm<<<dim3(3, 24), 256, 0, stream>>>(emb, idxTok, 512, WihDec, 1024, bihDec, giE, 1536, 512);
    k_encoder<<<64, 256, 0, stream>>>(giPre, giPost, WhhPre, WhhPost, bhhPre, bhhPost,
                                      encOut, hboxPre, hboxPost);
    k_gemm<<<dim3(32, 8), 256, 0, stream>>>(encOut, nullptr, 512, attnW + 512, 1024, attnB, encProj, 512, 512);
    k_fcenc<<<16, 256, 0, stream>>>(encOut, fcEncW, fcEncB, hBuf);
    k_encdot<<<32, 256, 0, stream>>>(encOut, wEff, encDot);
    k_edot4<<<192, 64, 0, stream>>>(emb, idxTok, wEff, eDot4);
    k_decoder<<<128, 128, 0, stream>>>(encOut, encProj, attnW, attnV, WihDec, WhhDec, bhhDec,
                                       giE, wEff, hBuf, hpM, scM, wM, hM, cBuf);
    k_final<<<192, 256, 0, stream>>>(encDot, cBuf, bEff, eDot4, outp);
}

// Round 4
// 4171.438 us; speedup vs baseline: 1.0498x; 1.0498x over previous
//
#include <hip/hip_runtime.h>
#include <cstdint>

typedef unsigned long long u64;

#define B_ 8
#define S_ 128
#define T_ 24
#define E_ 512
#define H_ 512
#define H3_ 1536
#define L_ 256
#define D_ 2048

__device__ __forceinline__ float fsig(float x) { return 1.0f / (1.0f + __expf(-x)); }
__device__ __forceinline__ float ftanh(float x) { return 1.0f - 2.0f / (1.0f + __expf(2.0f * x)); }
__device__ __forceinline__ float dot4(float4 a, float4 b) {
    return a.x * b.x + a.y * b.y + a.z * b.z + a.w * b.w;
}

// Coherent (LLC-point) ops: relaxed agent-scope atomics -> global_* sc0 sc1.
// No cache-maintenance instructions, bypass non-coherent L1/L2.
__device__ __forceinline__ int cohLoadI(const int* p) {
    return __hip_atomic_load((int*)p, __ATOMIC_RELAXED, __HIP_MEMORY_SCOPE_AGENT);
}
__device__ __forceinline__ void cohStoreI(int* p, int v) {
    __hip_atomic_store(p, v, __ATOMIC_RELAXED, __HIP_MEMORY_SCOPE_AGENT);
}
__device__ __forceinline__ void cohStoreF(float* p, float v) {
    __hip_atomic_store((unsigned*)p, __float_as_uint(v), __ATOMIC_RELAXED,
                       __HIP_MEMORY_SCOPE_AGENT);
}
__device__ __forceinline__ u64 cohLoad64(const float* p) {
    return __hip_atomic_load((u64*)p, __ATOMIC_RELAXED, __HIP_MEMORY_SCOPE_AGENT);
}

// ---------------------------------------------------------------------------
__global__ void k_init(const int* __restrict__ pre, const int* __restrict__ post,
                       const int* __restrict__ trg,
                       int* __restrict__ idxPre, int* __restrict__ idxPost,
                       int* __restrict__ idxTok, float* __restrict__ wEff,
                       float* __restrict__ c, int* __restrict__ doneEnc,
                       int* __restrict__ dflags) {
    int tid = blockIdx.x * 256 + threadIdx.x;  // grid 8 x 256 = 2048
    if (tid < 1024) {
        int s = tid >> 3, b = tid & 7;
        idxPre[tid]  = pre[b * S_ + s];
        idxPost[tid] = post[b * S_ + s];
    }
    if (tid < T_ * B_) {
        int t = tid >> 3, b = tid & 7;
        idxTok[tid] = (t == 0) ? pre[b * S_ + (S_ - 1)] : trg[b * T_ + (t - 1)];
    }
    if (tid < 256) c[tid] = 0.f;
    wEff[tid] = 0.f;
    if (tid < 64) doneEnc[tid] = 0;
    if (tid < 512) dflags[tid] = 0;
}

// ---------------------------------------------------------------------------
// Tiled f32 GEMM, z-fused pair: C[m][n] = sum_k A[m][k]*B[n][k] + bias[n]
// ---------------------------------------------------------------------------
__global__ __launch_bounds__(256) void k_gemm(
    const float* __restrict__ A, const int* __restrict__ Aidx0,
    const int* __restrict__ Aidx1, int lda,
    const float* __restrict__ B0, const float* __restrict__ B1, int ldb,
    const float* __restrict__ bias0, const float* __restrict__ bias1,
    float* __restrict__ C0, float* __restrict__ C1, int N, int K) {
    const int z = blockIdx.z;
    const int* Aidx = z ? Aidx1 : Aidx0;
    const float* Bm = z ? B1 : B0;
    const float* bias = z ? bias1 : bias0;
    float* C = z ? C1 : C0;
    __shared__ float As[16][68];
    __shared__ float Bs[16][68];
    const int m0 = blockIdx.x * 64, n0 = blockIdx.y * 64;
    const int tid = threadIdx.x;
    const int tm = tid >> 2;
    const int tk = (tid & 3) << 2;
    const int tx = tid & 15, ty = tid >> 4;
    const int am = m0 + tm;
    const float* Arow = A + (size_t)(Aidx ? Aidx[am] : am) * lda;
    const float* Brow = Bm + (size_t)(n0 + tm) * ldb;
    float acc[4][4] = {};
    for (int k0 = 0; k0 < K; k0 += 16) {
        float4 av = *(const float4*)(Arow + k0 + tk);
        float4 bv = *(const float4*)(Brow + k0 + tk);
        __syncthreads();
        As[tk][tm] = av.x; As[tk + 1][tm] = av.y; As[tk + 2][tm] = av.z; As[tk + 3][tm] = av.w;
        Bs[tk][tm] = bv.x; Bs[tk + 1][tm] = bv.y; Bs[tk + 2][tm] = bv.z; Bs[tk + 3][tm] = bv.w;
        __syncthreads();
#pragma unroll
        for (int k = 0; k < 16; ++k) {
            float4 a4 = *(const float4*)(&As[k][ty << 2]);
            float4 b4 = *(const float4*)(&Bs[k][tx << 2]);
            float ar[4] = {a4.x, a4.y, a4.z, a4.w};
            float br[4] = {b4.x, b4.y, b4.z, b4.w};
#pragma unroll
            for (int i = 0; i < 4; ++i)
#pragma unroll
                for (int j = 0; j < 4; ++j) acc[i][j] += ar[i] * br[j];
        }
    }
    float4 bb = bias ? *(const float4*)(bias + n0 + (tx << 2)) : make_float4(0.f, 0.f, 0.f, 0.f);
#pragma unroll
    for (int i = 0; i < 4; ++i) {
        int m = m0 + (ty << 2) + i;
        float4 o;
        o.x = acc[i][0] + bb.x; o.y = acc[i][1] + bb.y;
        o.z = acc[i][2] + bb.z; o.w = acc[i][3] + bb.w;
        *(float4*)(C + (size_t)m * N + n0 + (tx << 2)) = o;
    }
}

// ---------------------------------------------------------------------------
__global__ void k_weff(const float* __restrict__ fcW, const float* __restrict__ fcB,
                       const float* __restrict__ voW, const float* __restrict__ voB,
                       float* __restrict__ wEff, float* __restrict__ bEff) {
    __shared__ float red[256];
    int bx = blockIdx.x;
    if (bx < 128) {
        int cblk = bx & 7, q = bx >> 3;
        int col = cblk * 256 + threadIdx.x;
        int j0 = q * 128;
        float acc = 0.f;
        for (int j = j0; j < j0 + 128; ++j) acc += voW[j] * fcW[(size_t)j * D_ + col];
        atomicAdd(wEff + col, acc);
    } else {
        float p = 0.f;
        for (int j = threadIdx.x; j < D_; j += 256) p += voW[j] * fcB[j];
        red[threadIdx.x] = p;
        __syncthreads();
        for (int s = 128; s > 0; s >>= 1) {
            if (threadIdx.x < s) red[threadIdx.x] += red[threadIdx.x + s];
            __syncthreads();
        }
        if (threadIdx.x == 0) bEff[0] = red[0] + voB[0];
    }
}

// ---------------------------------------------------------------------------
// Encoder scan: 64 WGs (32 per GRU) x 256 thr. Thread = (col jj, batch b,
// k-half kh). Sync: per-WG epoch flag (parallel 32-thread poll), then bulk
// coherent dwordx2 h reload. No atomics, no fences.
// ---------------------------------------------------------------------------
__global__ __launch_bounds__(256) void k_encoder(
    const float* __restrict__ giPre, const float* __restrict__ giPost,
    const float* __restrict__ WhhPre, const float* __restrict__ WhhPost,
    const float* __restrict__ bhhPre, const float* __restrict__ bhhPost,
    float* __restrict__ encOut, float* __restrict__ hboxPre,
    float* __restrict__ hboxPost, int* __restrict__ doneEnc) {
    const int g = blockIdx.x >> 5;
    const int c = blockIdx.x & 31;
    const int j0 = c << 4;
    const float* gi = g ? giPost : giPre;
    const float* Whh = g ? WhhPost : WhhPre;
    const float* bhh = g ? bhhPost : bhhPre;
    float* hbox = g ? hboxPost : hboxPre;
    int* done = doneEnc + g * 32;

    const int tid = threadIdx.x;
    const int jj = tid & 15;
    const int b = (tid >> 4) & 7;
    const int kh = tid >> 7;
    const int j = j0 + jj;
    const int lane128 = tid & 127;

    __shared__ float hS[8 * 520];
    __shared__ float redE[384];

    const float4* wr = (const float4*)(Whh + (size_t)j * 512) + (kh << 6);
    const float4* wz = (const float4*)(Whh + (size_t)(512 + j) * 512) + (kh << 6);
    const float4* wn = (const float4*)(Whh + (size_t)(1024 + j) * 512) + (kh << 6);
    const float br_ = bhh[j], bz_ = bhh[512 + j], bn_ = bhh[1024 + j];

    for (int t = 0; t < S_; ++t) {
        if (t == 0) {
            for (int i = tid; i < 8 * 520; i += 256) hS[i] = 0.f;
        } else {
            if (tid < 32) {
                while (cohLoadI(done + tid) < t) __builtin_amdgcn_s_sleep(1);
            }
            __syncthreads();  // loads below issue only after flags observed
            const float* src = hbox + (size_t)((t & 1) ^ 1) * 4096;
#pragma unroll
            for (int q = 0; q < 8; ++q) {
                int i = (q * 256 + tid) * 2;
                u64 v = cohLoad64(src + i);
                int bb = i >> 9, k = i & 511;
                hS[bb * 520 + k] = __uint_as_float((unsigned)v);
                hS[bb * 520 + k + 1] = __uint_as_float((unsigned)(v >> 32));
            }
        }
        __syncthreads();
        const float4* h4 = (const float4*)(hS + b * 520) + (kh << 6);
        float ar = 0.f, az = 0.f, an = 0.f;
#pragma unroll 8
        for (int k = 0; k < 64; ++k) {
            float4 hv = h4[k];
            ar += dot4(wr[k], hv);
            az += dot4(wz[k], hv);
            an += dot4(wn[k], hv);
        }
        if (kh) {
            redE[lane128] = ar; redE[128 + lane128] = az; redE[256 + lane128] = an;
        }
        __syncthreads();
        if (!kh) {
            ar += redE[lane128] + br_;
            az += redE[128 + lane128] + bz_;
            an += redE[256 + lane128] + bn_;
            size_t gbase = ((size_t)t * 8 + b) * H3_;
            float r = fsig(gi[gbase + j] + ar);
            float z = fsig(gi[gbase + 512 + j] + az);
            float n = ftanh(gi[gbase + 1024 + j] + r * an);
            float h2 = (1.f - z) * n + z * hS[b * 520 + j];
            encOut[(((size_t)(b << 8) + (g << 7) + t) << 9) + j] = h2;
            cohStoreF(hbox + (size_t)(t & 1) * 4096 + (b << 9) + j, h2);
        }
        __syncthreads();  // drains all waves' stores before flag
        if (tid == 0) cohStoreI(done + c, t + 1);
    }
}

// ---------------------------------------------------------------------------
__global__ void k_fcenc(const float* __restrict__ encOut, const float* __restrict__ W,
                        const float* __restrict__ bias, float* __restrict__ h) {
    int o = blockIdx.x * 256 + threadIdx.x;  // grid 16 -> 4096
    int b = o >> 9, j = o & 511;
    const float4* w4 = (const float4*)(W + (size_t)j * 1024);
    const float4* pre4 = (const float4*)(encOut + (((size_t)(b << 8) + 127) << 9));
    const float4* post4 = (const float4*)(encOut + (((size_t)(b << 8) + 255) << 9));
    float acc = bias[j];
    for (int k = 0; k < 128; ++k) acc += dot4(w4[k], pre4[k]);
    for (int k = 0; k < 128; ++k) acc += dot4(w4[128 + k], post4[k]);
    h[o] = ftanh(acc);
}

// enc_dot[b*256+l] = enc_out[b,l,:] . w_eff[0:512]
__global__ void k_encdot(const float* __restrict__ encOut, const float* __restrict__ wEff,
                         float* __restrict__ encDot) {
    int wid = threadIdx.x >> 6, lane = threadIdx.x & 63;
    int gw = blockIdx.x * 4 + wid;  // grid 32 -> 128 waves
    for (int o = gw; o < 2048; o += 128) {
        const float* row = encOut + ((size_t)o << 9);
        float s = 0.f;
        for (int k = lane; k < 512; k += 64) s += row[k] * wEff[k];
        for (int off = 32; off; off >>= 1) s += __shfl_down(s, off);
        if (lane == 0) encDot[o] = s;
    }
}

// eDot4[t*8+b] = emb[tok[t,b]] . w_eff[1536:2048]
__global__ void k_edot4(const float* __restrict__ emb, const int* __restrict__ idxTok,
                        const float* __restrict__ wEff, float* __restrict__ eDot4) {
    int o = blockIdx.x;  // grid 192, block 64
    int lane = threadIdx.x;
    const float* row = emb + (size_t)idxTok[o] * E_;
    const float* w = wEff + 1536;
    float s = 0.f;
    for (int k = lane; k < 512; k += 64) s += row[k] * w[k];
    for (int off = 32; off; off >>= 1) s += __shfl_down(s, off);
    if (lane == 0) eDot4[o] = s;
}

// ---------------------------------------------------------------------------
// Decoder scan: 128 WGs x 128 thr, WG = (batch b, slice s). Per-batch sync
// domains (16 WGs). 4 phase flags/step, parallel 16-thread polls.
// ---------------------------------------------------------------------------
__global__ __launch_bounds__(128) void k_decoder(
    const float* __restrict__ encOut, const float* __restrict__ encProj,
    const float* __restrict__ attnW, const float* __restrict__ attnV,
    const float* __restrict__ WihDec, const float* __restrict__ WhhDec,
    const float* __restrict__ bhhDec, const float* __restrict__ giE,
    const float* __restrict__ wEff, const float* __restrict__ h0,
    float* __restrict__ hpB, float* __restrict__ scB, float* __restrict__ wB,
    float* __restrict__ hD, float* __restrict__ c, int* __restrict__ dflags) {
    const int tid = threadIdx.x;
    const int b = blockIdx.x >> 4, s = blockIdx.x & 15;
    int* fA = dflags + (0 * 8 + b) * 16;
    int* fB = dflags + (1 * 8 + b) * 16;
    int* fC = dflags + (2 * 8 + b) * 16;
    int* fD = dflags + (3 * 8 + b) * 16;

    __shared__ float hB[512];
    __shared__ float hpS[512];
    __shared__ float wSS[512];
    __shared__ float scS[256];
    __shared__ float aS[256];
    __shared__ float gh2S[96];
    __shared__ float gi2S[96];
    __shared__ float red[32][5];
    __shared__ float red2[16][9];
    __shared__ float red3[32][5];
    __shared__ float redS[128];

    for (int t = 0; t < T_; ++t) {
        // ---- obtain h ----
        if (t == 0) {
#pragma unroll
            for (int q = 0; q < 4; ++q) hB[q * 128 + tid] = h0[(b << 9) + q * 128 + tid];
        } else {
            if (tid < 16) {
                while (cohLoadI(fD + tid) < t) __builtin_amdgcn_s_sleep(1);
            }
            __syncthreads();
#pragma unroll
            for (int q = 0; q < 2; ++q) {
                int i = (q * 128 + tid) * 2;
                u64 v = cohLoad64(hD + (b << 9) + i);
                hB[i] = __uint_as_float((unsigned)v);
                hB[i + 1] = __uint_as_float((unsigned)(v >> 32));
            }
        }
        __syncthreads();
        // ---- A: hp slice -> publish ----
        {
            int r = tid & 31, q = tid >> 5;
            const float4* w4 = (const float4*)(attnW + (size_t)(s * 32 + r) * 1024 + q * 128);
            const float4* h4 = (const float4*)(hB + q * 128);
            float acc = 0.f;
#pragma unroll
            for (int k = 0; k < 32; ++k) acc += dot4(w4[k], h4[k]);
            red[r][q] = acc;
        }
        __syncthreads();
        if (tid < 32) {
            float a = red[tid][0] + red[tid][1] + red[tid][2] + red[tid][3];
            cohStoreF(hpB + (b << 9) + s * 32 + tid, a);
        }
        __syncthreads();
        if (tid == 0) cohStoreI(fA + s, t + 1);
        // gh2 slice (LDS-only; overlaps peers' phase A)
        if (tid < 96) {
            int gate = tid >> 5, jjj = tid & 31;
            int n = gate * 512 + s * 32 + jjj;
            const float4* w4 = (const float4*)(WhhDec + (size_t)n * 512);
            const float4* h4 = (const float4*)hB;
            float acc = bhhDec[n];
#pragma unroll 4
            for (int k = 0; k < 128; ++k) acc += dot4(w4[k], h4[k]);
            gh2S[tid] = acc;
        }
        // ---- B: obtain hp; scores -> publish ----
        if (tid < 16) {
            while (cohLoadI(fA + tid) < t + 1) __builtin_amdgcn_s_sleep(1);
        }
        __syncthreads();
#pragma unroll
        for (int q = 0; q < 2; ++q) {
            int i = (q * 128 + tid) * 2;
            u64 v = cohLoad64(hpB + (b << 9) + i);
            hpS[i] = __uint_as_float((unsigned)v);
            hpS[i + 1] = __uint_as_float((unsigned)(v >> 32));
        }
        __syncthreads();
        {
            int r = tid & 15, q = tid >> 4;
            int l = s * 16 + r;
            const float* ep = encProj + (((size_t)(b << 8) + l) << 9) + q * 64;
            const float* hp = hpS + q * 64;
            const float* av = attnV + q * 64;
            float acc = 0.f;
#pragma unroll 8
            for (int k = 0; k < 64; ++k) acc += av[k] * ftanh(ep[k] + hp[k]);
            red2[r][q] = acc;
        }
        __syncthreads();
        if (tid < 16) {
            float a = 0.f;
#pragma unroll
            for (int q = 0; q < 8; ++q) a += red2[tid][q];
            cohStoreF(scB + (b << 8) + s * 16 + tid, a);
        }
        __syncthreads();
        if (tid == 0) cohStoreI(fB + s, t + 1);
        // ---- C: obtain scores; softmax; weighted -> publish ----
        if (tid < 16) {
            while (cohLoadI(fB + tid) < t + 1) __builtin_amdgcn_s_sleep(1);
        }
        __syncthreads();
        {
            int i = tid * 2;
            u64 v = cohLoad64(scB + (b << 8) + i);
            scS[i] = __uint_as_float((unsigned)v);
            scS[i + 1] = __uint_as_float((unsigned)(v >> 32));
        }
        __syncthreads();
        {
            float s0 = scS[tid], s1 = scS[128 + tid];
            redS[tid] = fmaxf(s0, s1);
            __syncthreads();
            for (int st = 64; st > 0; st >>= 1) {
                if (tid < st) redS[tid] = fmaxf(redS[tid], redS[tid + st]);
                __syncthreads();
            }
            float mx = redS[0];
            __syncthreads();
            float e0 = __expf(s0 - mx), e1 = __expf(s1 - mx);
            redS[tid] = e0 + e1;
            __syncthreads();
            for (int st = 64; st > 0; st >>= 1) {
                if (tid < st) redS[tid] += redS[tid + st];
                __syncthreads();
            }
            float inv = 1.f / redS[0];
            aS[tid] = e0 * inv;
            aS[128 + tid] = e1 * inv;
        }
        __syncthreads();
        {
            int jjj = tid & 31, p = tid >> 5;
            int hc = s * 32 + jjj;
            float acc = 0.f;
            for (int l = p * 64; l < p * 64 + 64; ++l)
                acc += aS[l] * encOut[(((size_t)(b << 8) + l) << 9) + hc];
            red3[jjj][p] = acc;
        }
        __syncthreads();
        if (tid < 32) {
            float a = red3[tid][0] + red3[tid][1] + red3[tid][2] + red3[tid][3];
            cohStoreF(wB + (b << 9) + s * 32 + tid, a);
        }
        __syncthreads();
        if (tid == 0) cohStoreI(fC + s, t + 1);
        // ---- D: obtain weighted; gi2; GRU update -> publish h ----
        if (tid < 16) {
            while (cohLoadI(fC + tid) < t + 1) __builtin_amdgcn_s_sleep(1);
        }
        __syncthreads();
#pragma unroll
        for (int q = 0; q < 2; ++q) {
            int i = (q * 128 + tid) * 2;
            u64 v = cohLoad64(wB + (b << 9) + i);
            wSS[i] = __uint_as_float((unsigned)v);
            wSS[i + 1] = __uint_as_float((unsigned)(v >> 32));
        }
        __syncthreads();
        if (tid < 96) {
            int gate = tid >> 5, jjj = tid & 31;
            int n = gate * 512 + s * 32 + jjj;
            const float4* w4 = (const float4*)(WihDec + (size_t)n * 1024 + 512);
            const float4* x4 = (const float4*)wSS;
            float acc = giE[((size_t)(t << 3) + b) * H3_ + n];
#pragma unroll 4
            for (int k = 0; k < 128; ++k) acc += dot4(w4[k], x4[k]);
            gi2S[tid] = acc;
        }
        __syncthreads();
        if (tid < 32) {
            int j = s * 32 + tid;
            float r = fsig(gi2S[tid] + gh2S[tid]);
            float z = fsig(gi2S[32 + tid] + gh2S[32 + tid]);
            float nn = ftanh(gi2S[64 + tid] + r * gh2S[64 + tid]);
            float h2 = (1.f - z) * nn + z * hB[j];
            cohStoreF(hD + (b << 9) + j, h2);
            float pc = h2 * wEff[1024 + j] + wSS[j] * wEff[512 + j];
#pragma unroll
            for (int off = 16; off; off >>= 1) pc += __shfl_down(pc, off);
            if (tid == 0) atomicAdd(c + b * T_ + t, pc);
        }
        __syncthreads();
        if (tid == 0) cohStoreI(fD + s, t + 1);
    }
}

// out = enc_dot[b,l] + c[b,t] + bEff + eDot4[t,b]
__global__ void k_final(const float* __restrict__ encDot, const float* __restrict__ c,
                        const float* __restrict__ bEff, const float* __restrict__ eDot4,
                        float* __restrict__ out) {
    int idx = blockIdx.x * 256 + threadIdx.x;  // grid 192 -> 49152
    const int half = B_ * T_ * S_;
    int w = idx < half ? idx : idx - half;
    int b = w / (T_ * S_);
    int r = w % (T_ * S_);
    int t = r / S_, sidx = r % S_;
    int l = (idx < half) ? sidx : (S_ + sidx);
    out[idx] = encDot[b * L_ + l] + c[b * T_ + t] + bEff[0] + eDot4[t * 8 + b];
}

// ---------------------------------------------------------------------------
extern "C" void kernel_launch(void* const* d_in, const int* in_sizes, int n_in,
                              void* d_out, int out_size, void* d_ws, size_t ws_size,
                              hipStream_t stream) {
    const int* pre = (const int*)d_in[0];
    const int* post = (const int*)d_in[1];
    const int* trg = (const int*)d_in[2];
    const float* emb = (const float*)d_in[3];
    const float* WihPre = (const float*)d_in[4];
    const float* WhhPre = (const float*)d_in[5];
    const float* bihPre = (const float*)d_in[6];
    const float* bhhPre = (const float*)d_in[7];
    const float* WihPost = (const float*)d_in[8];
    const float* WhhPost = (const float*)d_in[9];
    const float* bihPost = (const float*)d_in[10];
    const float* bhhPost = (const float*)d_in[11];
    const float* fcEncW = (const float*)d_in[12];
    const float* fcEncB = (const float*)d_in[13];
    const float* attnW = (const float*)d_in[14];
    const float* attnB = (const float*)d_in[15];
    const float* attnV = (const float*)d_in[16];
    const float* WihDec = (const float*)d_in[17];
    const float* WhhDec = (const float*)d_in[18];
    const float* bihDec = (const float*)d_in[19];
    const float* bhhDec = (const float*)d_in[20];
    const float* fcHidW = (const float*)d_in[21];
    const float* fcHidB = (const float*)d_in[22];
    const float* fcOutW = (const float*)d_in[23];
    const float* fcOutB = (const float*)d_in[24];
    float* outp = (float*)d_out;

    float* base = (float*)d_ws;
    size_t off = 0;
    auto alloc = [&](size_t n) {
        float* p = base + off;
        off += (n + 63) & ~(size_t)63;
        return p;
    };
    float* giPre = alloc(1024 * 1536);
    float* giPost = alloc(1024 * 1536);
    float* giE = alloc(192 * 1536);
    float* encOut = alloc(8 * 256 * 512);
    float* encProj = alloc(8 * 256 * 512);
    float* wEff = alloc(2048);
    float* bEff = alloc(64);
    float* encDot = alloc(2048);
    float* eDot4 = alloc(256);
    float* hBuf = alloc(4096);
    float* cBuf = alloc(256);
    float* hboxPre = alloc(2 * 4096);
    float* hboxPost = alloc(2 * 4096);
    float* hpB = alloc(4096);
    float* scB = alloc(2048);
    float* wB = alloc(4096);
    float* hD = alloc(4096);
    int* doneEnc = (int*)alloc(64);
    int* dflags = (int*)alloc(512);
    int* idxPre = (int*)alloc(1024);
    int* idxPost = (int*)alloc(1024);
    int* idxTok = (int*)alloc(256);

    k_init<<<8, 256, 0, stream>>>(pre, post, trg, idxPre, idxPost, idxTok, wEff, cBuf,
                                  doneEnc, dflags);
    k_weff<<<129, 256, 0, stream>>>(fcHidW, fcHidB, fcOutW, fcOutB, wEff, bEff);
    k_gemm<<<dim3(16, 24, 2), 256, 0, stream>>>(emb, idxPre, idxPost, 512,
                                                WihPre, WihPost, 512, bihPre, bihPost,
                                                giPre, giPost, 1536, 512);
    k_gemm<<<dim3(3, 24, 1), 256, 0, stream>>>(emb, idxTok, idxTok, 512,
                                               WihDec, WihDec, 1024, bihDec, bihDec,
                                               giE, giE, 1536, 512);
    k_encoder<<<64, 256, 0, stream>>>(giPre, giPost, WhhPre, WhhPost, bhhPre, bhhPost,
                                      encOut, hboxPre, hboxPost, doneEnc);
    k_gemm<<<dim3(32, 8, 1), 256, 0, stream>>>(encOut, nullptr, nullptr, 512,
                                               attnW + 512, attnW + 512, 1024, attnB, attnB,
                                               encProj, encProj, 512, 512);
    k_fcenc<<<16, 256, 0, stream>>>(encOut, fcEncW, fcEncB, hBuf);
    k_encdot<<<32, 256, 0, stream>>>(encOut, wEff, encDot);
    k_edot4<<<192, 64, 0, stream>>>(emb, idxTok, wEff, eDot4);
    k_decoder<<<128, 128, 0, stream>>>(encOut, encProj, attnW, attnV, WihDec, WhhDec, bhhDec,
                                       giE, wEff, hBuf, hpB, scB, wB, hD, cBuf, dflags);
    k_final<<<192, 256, 0, stream>>>(encDot, cBuf, bEff, eDot4, outp);
}

// Round 6
// 4069.130 us; speedup vs baseline: 1.0762x; 1.0251x over previous
//
#include <hip/hip_runtime.h>
#include <cstdint>

typedef unsigned long long u64;
typedef float f32x4 __attribute__((ext_vector_type(4)));
typedef float f32x2 __attribute__((ext_vector_type(2)));

#define B_ 8
#define S_ 128
#define T_ 24
#define E_ 512
#define H_ 512
#define H3_ 1536
#define L_ 256
#define D_ 2048

__device__ __forceinline__ float fsig(float x) { return 1.0f / (1.0f + __expf(-x)); }
__device__ __forceinline__ float ftanh(float x) { return 1.0f - 2.0f / (1.0f + __expf(2.0f * x)); }
__device__ __forceinline__ float dot4(float4 a, float4 b) {
    return a.x * b.x + a.y * b.y + a.z * b.z + a.w * b.w;
}

// Coherent (LLC-point) ops. Relaxed agent-scope atomics -> global_* sc0 sc1:
// bypass non-coherent L1/L2, no cache-maintenance instructions.
__device__ __forceinline__ int cohLoadI(const int* p) {
    return __hip_atomic_load((int*)p, __ATOMIC_RELAXED, __HIP_MEMORY_SCOPE_AGENT);
}
__device__ __forceinline__ void cohStoreF(float* p, float v) {
    __hip_atomic_store((unsigned*)p, __float_as_uint(v), __ATOMIC_RELAXED,
                       __HIP_MEMORY_SCOPE_AGENT);
}
// Wide LLC loads (no 16B atomic intrinsic exists): barrier provides ordering,
// sc0 sc1 provides coherence. Batched variant: one waitcnt per 4 loads.
__device__ __forceinline__ f32x4 llcLoadF4(const float* p) {
    f32x4 v;
    asm volatile("global_load_dwordx4 %0, %1, off sc0 sc1\n\ts_waitcnt vmcnt(0)"
                 : "=&v"(v) : "v"(p) : "memory");
    return v;
}
__device__ __forceinline__ f32x2 llcLoadF2(const float* p) {
    f32x2 v;
    asm volatile("global_load_dwordx2 %0, %1, off sc0 sc1\n\ts_waitcnt vmcnt(0)"
                 : "=&v"(v) : "v"(p) : "memory");
    return v;
}
__device__ __forceinline__ void llcLoad4x(const float* p0, const float* p1,
                                          const float* p2, const float* p3,
                                          f32x4& a, f32x4& b, f32x4& c, f32x4& d) {
    asm volatile(
        "global_load_dwordx4 %0, %4, off sc0 sc1\n\t"
        "global_load_dwordx4 %1, %5, off sc0 sc1\n\t"
        "global_load_dwordx4 %2, %6, off sc0 sc1\n\t"
        "global_load_dwordx4 %3, %7, off sc0 sc1\n\t"
        "s_waitcnt vmcnt(0)"
        : "=&v"(a), "=&v"(b), "=&v"(c), "=&v"(d)
        : "v"(p0), "v"(p1), "v"(p2), "v"(p3)
        : "memory");
}
__device__ __forceinline__ void pollGE(const int* p, int tgt) {
    int v = cohLoadI(p);
    while (v < tgt) {
        __builtin_amdgcn_s_sleep(2);
        v = cohLoadI(p);
    }
}

// ---------------------------------------------------------------------------
__global__ void k_init(const int* __restrict__ pre, const int* __restrict__ post,
                       const int* __restrict__ trg,
                       int* __restrict__ idxPre, int* __restrict__ idxPost,
                       int* __restrict__ idxTok, float* __restrict__ wEff,
                       float* __restrict__ c, int* __restrict__ encCnt,
                       int* __restrict__ dcnt) {
    int tid = blockIdx.x * 256 + threadIdx.x;  // grid 8 x 256 = 2048
    if (tid < 1024) {
        int s = tid >> 3, b = tid & 7;
        idxPre[tid]  = pre[b * S_ + s];
        idxPost[tid] = post[b * S_ + s];
    }
    if (tid < T_ * B_) {
        int t = tid >> 3, b = tid & 7;
        idxTok[tid] = (t == 0) ? pre[b * S_ + (S_ - 1)] : trg[b * T_ + (t - 1)];
    }
    if (tid < 256) c[tid] = 0.f;
    wEff[tid] = 0.f;
    if (tid < 128) encCnt[tid] = 0;
    dcnt[tid] = 0;  // 2048 ints
}

// ---------------------------------------------------------------------------
// Tiled f32 GEMM, z-fused pair: C[m][n] = sum_k A[m][k]*B[n][k] + bias[n]
// ---------------------------------------------------------------------------
__global__ __launch_bounds__(256) void k_gemm(
    const float* __restrict__ A, const int* __restrict__ Aidx0,
    const int* __restrict__ Aidx1, int lda,
    const float* __restrict__ B0, const float* __restrict__ B1, int ldb,
    const float* __restrict__ bias0, const float* __restrict__ bias1,
    float* __restrict__ C0, float* __restrict__ C1, int N, int K) {
    const int z = blockIdx.z;
    const int* Aidx = z ? Aidx1 : Aidx0;
    const float* Bm = z ? B1 : B0;
    const float* bias = z ? bias1 : bias0;
    float* C = z ? C1 : C0;
    __shared__ float As[16][68];
    __shared__ float Bs[16][68];
    const int m0 = blockIdx.x * 64, n0 = blockIdx.y * 64;
    const int tid = threadIdx.x;
    const int tm = tid >> 2;
    const int tk = (tid & 3) << 2;
    const int tx = tid & 15, ty = tid >> 4;
    const int am = m0 + tm;
    const float* Arow = A + (size_t)(Aidx ? Aidx[am] : am) * lda;
    const float* Brow = Bm + (size_t)(n0 + tm) * ldb;
    float acc[4][4] = {};
    for (int k0 = 0; k0 < K; k0 += 16) {
        float4 av = *(const float4*)(Arow + k0 + tk);
        float4 bv = *(const float4*)(Brow + k0 + tk);
        __syncthreads();
        As[tk][tm] = av.x; As[tk + 1][tm] = av.y; As[tk + 2][tm] = av.z; As[tk + 3][tm] = av.w;
        Bs[tk][tm] = bv.x; Bs[tk + 1][tm] = bv.y; Bs[tk + 2][tm] = bv.z; Bs[tk + 3][tm] = bv.w;
        __syncthreads();
#pragma unroll
        for (int k = 0; k < 16; ++k) {
            float4 a4 = *(const float4*)(&As[k][ty << 2]);
            float4 b4 = *(const float4*)(&Bs[k][tx << 2]);
            float ar[4] = {a4.x, a4.y, a4.z, a4.w};
            float br[4] = {b4.x, b4.y, b4.z, b4.w};
#pragma unroll
            for (int i = 0; i < 4; ++i)
#pragma unroll
                for (int j = 0; j < 4; ++j) acc[i][j] += ar[i] * br[j];
        }
    }
    float4 bb = bias ? *(const float4*)(bias + n0 + (tx << 2)) : make_float4(0.f, 0.f, 0.f, 0.f);
#pragma unroll
    for (int i = 0; i < 4; ++i) {
        int m = m0 + (ty << 2) + i;
        float4 o;
        o.x = acc[i][0] + bb.x; o.y = acc[i][1] + bb.y;
        o.z = acc[i][2] + bb.z; o.w = acc[i][3] + bb.w;
        *(float4*)(C + (size_t)m * N + n0 + (tx << 2)) = o;
    }
}

// ---------------------------------------------------------------------------
__global__ void k_weff(const float* __restrict__ fcW, const float* __restrict__ fcB,
                       const float* __restrict__ voW, const float* __restrict__ voB,
                       float* __restrict__ wEff, float* __restrict__ bEff) {
    __shared__ float red[256];
    int bx = blockIdx.x;
    if (bx < 128) {
        int cblk = bx & 7, q = bx >> 3;
        int col = cblk * 256 + threadIdx.x;
        int j0 = q * 128;
        float acc = 0.f;
        for (int j = j0; j < j0 + 128; ++j) acc += voW[j] * fcW[(size_t)j * D_ + col];
        atomicAdd(wEff + col, acc);
    } else {
        float p = 0.f;
        for (int j = threadIdx.x; j < D_; j += 256) p += voW[j] * fcB[j];
        red[threadIdx.x] = p;
        __syncthreads();
        for (int s = 128; s > 0; s >>= 1) {
            if (threadIdx.x < s) red[threadIdx.x] += red[threadIdx.x + s];
            __syncthreads();
        }
        if (threadIdx.x == 0) bEff[0] = red[0] + voB[0];
    }
}

// ---------------------------------------------------------------------------
// Encoder scan: 64 WGs (32 per GRU) x 256 thr, WG=(g,c). Sync: one counter
// per GRU (256B apart), 1 poller/WG with s_sleep backoff. h broadcast via
// batched dwordx4 sc0 sc1 loads. Double-buffered hbox by step parity.
// ---------------------------------------------------------------------------
__global__ __launch_bounds__(256) void k_encoder(
    const float* __restrict__ giPre, const float* __restrict__ giPost,
    const float* __restrict__ WhhPre, const float* __restrict__ WhhPost,
    const float* __restrict__ bhhPre, const float* __restrict__ bhhPost,
    float* __restrict__ encOut, float* __restrict__ hboxPre,
    float* __restrict__ hboxPost, int* __restrict__ encCnt) {
    const int g = blockIdx.x >> 5;
    const int c = blockIdx.x & 31;
    const int j0 = c << 4;
    const float* gi = g ? giPost : giPre;
    const float* Whh = g ? WhhPost : WhhPre;
    const float* bhh = g ? bhhPost : bhhPre;
    float* hbox = g ? hboxPost : hboxPre;
    int* cnt = encCnt + g * 64;  // 256B apart

    const int tid = threadIdx.x;
    const int jj = tid & 15;
    const int b = (tid >> 4) & 7;
    const int kh = tid >> 7;
    const int j = j0 + jj;
    const int lane128 = tid & 127;

    __shared__ float hS[8 * 520];
    __shared__ float redE[384];

    const float4* wr = (const float4*)(Whh + (size_t)j * 512) + (kh << 6);
    const float4* wz = (const float4*)(Whh + (size_t)(512 + j) * 512) + (kh << 6);
    const float4* wn = (const float4*)(Whh + (size_t)(1024 + j) * 512) + (kh << 6);
    const float br_ = bhh[j], bz_ = bhh[512 + j], bn_ = bhh[1024 + j];

    for (int t = 0; t < S_; ++t) {
        if (t == 0) {
            for (int i = tid; i < 8 * 520; i += 256) hS[i] = 0.f;
        } else {
            const float* src = hbox + (size_t)((t & 1) ^ 1) * 4096;
            f32x4 a0, a1, a2, a3;
            llcLoad4x(src + (size_t)tid * 4, src + (size_t)(256 + tid) * 4,
                      src + (size_t)(512 + tid) * 4, src + (size_t)(768 + tid) * 4,
                      a0, a1, a2, a3);
            int i0 = tid, i1 = 256 + tid, i2 = 512 + tid, i3 = 768 + tid;  // f4 idx
            *(f32x4*)(hS + (i0 >> 7) * 520 + ((i0 & 127) << 2)) = a0;
            *(f32x4*)(hS + (i1 >> 7) * 520 + ((i1 & 127) << 2)) = a1;
            *(f32x4*)(hS + (i2 >> 7) * 520 + ((i2 & 127) << 2)) = a2;
            *(f32x4*)(hS + (i3 >> 7) * 520 + ((i3 & 127) << 2)) = a3;
        }
        __syncthreads();
        // gi prefetch: issued now, consumed after the gate dots (hides HBM)
        float gir = 0.f, giz = 0.f, gin = 0.f;
        if (!kh) {
            size_t gbase = ((size_t)t * 8 + b) * H3_;
            gir = gi[gbase + j];
            giz = gi[gbase + 512 + j];
            gin = gi[gbase + 1024 + j];
        }
        const float4* h4 = (const float4*)(hS + b * 520) + (kh << 6);
        float ar = 0.f, az = 0.f, an = 0.f;
#pragma unroll 8
        for (int k = 0; k < 64; ++k) {
            float4 hv = h4[k];
            ar += dot4(wr[k], hv);
            az += dot4(wz[k], hv);
            an += dot4(wn[k], hv);
        }
        if (kh) {
            redE[lane128] = ar; redE[128 + lane128] = az; redE[256 + lane128] = an;
        }
        __syncthreads();
        if (!kh) {
            ar += redE[lane128] + br_;
            az += redE[128 + lane128] + bz_;
            an += redE[256 + lane128] + bn_;
            float r = fsig(gir + ar);
            float z = fsig(giz + az);
            float n = ftanh(gin + r * an);
            float h2 = (1.f - z) * n + z * hS[b * 520 + j];
            encOut[(((size_t)(b << 8) + (g << 7) + t) << 9) + j] = h2;
            cohStoreF(hbox + (size_t)(t & 1) * 4096 + (b << 9) + j, h2);
        }
        __syncthreads();  // per-wave vmcnt(0) drain before barrier release
        if (tid == 0) {
            atomicAdd(cnt, 1);      // no-return device-scope add
            pollGE(cnt, 32 * (t + 1));
        }
        __syncthreads();
    }
}

// ---------------------------------------------------------------------------
__global__ void k_fcenc(const float* __restrict__ encOut, const float* __restrict__ W,
                        const float* __restrict__ bias, float* __restrict__ h) {
    int o = blockIdx.x * 256 + threadIdx.x;  // grid 16 -> 4096
    int b = o >> 9, j = o & 511;
    const float4* w4 = (const float4*)(W + (size_t)j * 1024);
    const float4* pre4 = (const float4*)(encOut + (((size_t)(b << 8) + 127) << 9));
    const float4* post4 = (const float4*)(encOut + (((size_t)(b << 8) + 255) << 9));
    float acc = bias[j];
    for (int k = 0; k < 128; ++k) acc += dot4(w4[k], pre4[k]);
    for (int k = 0; k < 128; ++k) acc += dot4(w4[128 + k], post4[k]);
    h[o] = ftanh(acc);
}

// enc_dot[b*256+l] = enc_out[b,l,:] . w_eff[0:512]
__global__ void k_encdot(const float* __restrict__ encOut, const float* __restrict__ wEff,
                         float* __restrict__ encDot) {
    int wid = threadIdx.x >> 6, lane = threadIdx.x & 63;
    int gw = blockIdx.x * 4 + wid;  // grid 32 -> 128 waves
    for (int o = gw; o < 2048; o += 128) {
        const float* row = encOut + ((size_t)o << 9);
        float s = 0.f;
        for (int k = lane; k < 512; k += 64) s += row[k] * wEff[k];
        for (int off = 32; off; off >>= 1) s += __shfl_down(s, off);
        if (lane == 0) encDot[o] = s;
    }
}

// eDot4[t*8+b] = emb[tok[t,b]] . w_eff[1536:2048]
__global__ void k_edot4(const float* __restrict__ emb, const int* __restrict__ idxTok,
                        const float* __restrict__ wEff, float* __restrict__ eDot4) {
    int o = blockIdx.x;  // grid 192, block 64
    int lane = threadIdx.x;
    const float* row = emb + (size_t)idxTok[o] * E_;
    const float* w = wEff + 1536;
    float s = 0.f;
    for (int k = lane; k < 512; k += 64) s += row[k] * w[k];
    for (int off = 32; off; off >>= 1) s += __shfl_down(s, off);
    if (lane == 0) eDot4[o] = s;
}

// ---------------------------------------------------------------------------
// Decoder scan: 128 WGs x 128 thr, WG=(b, s). Per-(phase,batch) counters
// (256B apart), 1 poller/WG, x4 coherent loads. gh2 overlaps phase-A wait.
// ---------------------------------------------------------------------------
__global__ __launch_bounds__(128) void k_decoder(
    const float* __restrict__ encOut, const float* __restrict__ encProj,
    const float* __restrict__ attnW, const float* __restrict__ attnV,
    const float* __restrict__ WihDec, const float* __restrict__ WhhDec,
    const float* __restrict__ bhhDec, const float* __restrict__ giE,
    const float* __restrict__ wEff, const float* __restrict__ h0,
    float* __restrict__ hpB, float* __restrict__ scB, float* __restrict__ wB,
    float* __restrict__ hD, float* __restrict__ c, int* __restrict__ dcnt) {
    const int tid = threadIdx.x;
    const int b = blockIdx.x >> 4, s = blockIdx.x & 15;
    int* cA = dcnt + (0 * 8 + b) * 64;
    int* cB = dcnt + (1 * 8 + b) * 64;
    int* cC = dcnt + (2 * 8 + b) * 64;
    int* cD = dcnt + (3 * 8 + b) * 64;

    __shared__ float hB[512];
    __shared__ float hpS[512];
    __shared__ float wSS[512];
    __shared__ float scS[256];
    __shared__ float aS[256];
    __shared__ float gh2S[96];
    __shared__ float gi2S[96];
    __shared__ float red[32][5];
    __shared__ float red2[16][9];
    __shared__ float red3[32][5];
    __shared__ float redS[128];

    for (int t = 0; t < T_; ++t) {
        // ---- obtain h ----
        if (t == 0) {
#pragma unroll
            for (int q = 0; q < 4; ++q) hB[q * 128 + tid] = h0[(b << 9) + q * 128 + tid];
        } else {
            if (tid == 0) pollGE(cD, 16 * t);
            __syncthreads();
            f32x4 v = llcLoadF4(hD + (b << 9) + (size_t)tid * 4);
            *(f32x4*)(hB + tid * 4) = v;
        }
        __syncthreads();
        // ---- A: hp slice -> publish ----
        {
            int r = tid & 31, q = tid >> 5;
            const float4* w4 = (const float4*)(attnW + (size_t)(s * 32 + r) * 1024 + q * 128);
            const float4* h4 = (const float4*)(hB + q * 128);
            float acc = 0.f;
#pragma unroll
            for (int k = 0; k < 32; ++k) acc += dot4(w4[k], h4[k]);
            red[r][q] = acc;
        }
        __syncthreads();
        if (tid < 32) {
            float a = red[tid][0] + red[tid][1] + red[tid][2] + red[tid][3];
            cohStoreF(hpB + (b << 9) + s * 32 + tid, a);
        }
        __syncthreads();
        if (tid == 0) atomicAdd(cA, 1);
        // gh2 slice (LDS-only): overlaps peers' phase A
        if (tid < 96) {
            int gate = tid >> 5, jjj = tid & 31;
            int n = gate * 512 + s * 32 + jjj;
            const float4* w4 = (const float4*)(WhhDec + (size_t)n * 512);
            const float4* h4 = (const float4*)hB;
            float acc = bhhDec[n];
#pragma unroll 4
            for (int k = 0; k < 128; ++k) acc += dot4(w4[k], h4[k]);
            gh2S[tid] = acc;
        }
        if (tid == 0) pollGE(cA, 16 * (t + 1));
        __syncthreads();
        // ---- B: obtain hp; scores -> publish ----
        {
            f32x4 v = llcLoadF4(hpB + (b << 9) + (size_t)tid * 4);
            *(f32x4*)(hpS + tid * 4) = v;
        }
        __syncthreads();
        {
            int r = tid & 15, q = tid >> 4;
            int l = s * 16 + r;
            const float* ep = encProj + (((size_t)(b << 8) + l) << 9) + q * 64;
            const float* hp = hpS + q * 64;
            const float* av = attnV + q * 64;
            float acc = 0.f;
#pragma unroll 8
            for (int k = 0; k < 64; ++k) acc += av[k] * ftanh(ep[k] + hp[k]);
            red2[r][q] = acc;
        }
        __syncthreads();
        if (tid < 16) {
            float a = 0.f;
#pragma unroll
            for (int q = 0; q < 8; ++q) a += red2[tid][q];
            cohStoreF(scB + (b << 8) + s * 16 + tid, a);
        }
        __syncthreads();
        if (tid == 0) {
            atomicAdd(cB, 1);
            pollGE(cB, 16 * (t + 1));
        }
        __syncthreads();
        // ---- C: obtain scores; softmax; weighted -> publish ----
        {
            f32x2 v = llcLoadF2(scB + (b << 8) + (size_t)tid * 2);
            scS[tid * 2] = v.x;
            scS[tid * 2 + 1] = v.y;
        }
        __syncthreads();
        {
            float s0 = scS[tid], s1 = scS[128 + tid];
            redS[tid] = fmaxf(s0, s1);
            __syncthreads();
            for (int st = 64; st > 0; st >>= 1) {
                if (tid < st) redS[tid] = fmaxf(redS[tid], redS[tid + st]);
                __syncthreads();
            }
            float mx = redS[0];
            __syncthreads();
            float e0 = __expf(s0 - mx), e1 = __expf(s1 - mx);
            redS[tid] = e0 + e1;
            __syncthreads();
            for (int st = 64; st > 0; st >>= 1) {
                if (tid < st) redS[tid] += redS[tid + st];
                __syncthreads();
            }
            float inv = 1.f / redS[0];
            aS[tid] = e0 * inv;
            aS[128 + tid] = e1 * inv;
        }
        __syncthreads();
        {
            int jjj = tid & 31, p = tid >> 5;
            int hc = s * 32 + jjj;
            float acc = 0.f;
            for (int l = p * 64; l < p * 64 + 64; ++l)
                acc += aS[l] * encOut[(((size_t)(b << 8) + l) << 9) + hc];
            red3[jjj][p] = acc;
        }
        __syncthreads();
        if (tid < 32) {
            float a = red3[tid][0] + red3[tid][1] + red3[tid][2] + red3[tid][3];
            cohStoreF(wB + (b << 9) + s * 32 + tid, a);
        }
        __syncthreads();
        if (tid == 0) {
            atomicAdd(cC, 1);
            pollGE(cC, 16 * (t + 1));
        }
        __syncthreads();
        // ---- D: obtain weighted; gi2; GRU update -> publish h ----
        {
            f32x4 v = llcLoadF4(wB + (b << 9) + (size_t)tid * 4);
            *(f32x4*)(wSS + tid * 4) = v;
        }
        __syncthreads();
        if (tid < 96) {
            int gate = tid >> 5, jjj = tid & 31;
            int n = gate * 512 + s * 32 + jjj;
            const float4* w4 = (const float4*)(WihDec + (size_t)n * 1024 + 512);
            const float4* x4 = (const float4*)wSS;
            float acc = giE[((size_t)(t << 3) + b) * H3_ + n];
#pragma unroll 4
            for (int k = 0; k < 128; ++k) acc += dot4(w4[k], x4[k]);
            gi2S[tid] = acc;
        }
        __syncthreads();
        if (tid < 32) {
            int j = s * 32 + tid;
            float r = fsig(gi2S[tid] + gh2S[tid]);
            float z = fsig(gi2S[32 + tid] + gh2S[32 + tid]);
            float nn = ftanh(gi2S[64 + tid] + r * gh2S[64 + tid]);
            float h2 = (1.f - z) * nn + z * hB[j];
            cohStoreF(hD + (b << 9) + j, h2);
            float pc = h2 * wEff[1024 + j] + wSS[j] * wEff[512 + j];
#pragma unroll
            for (int off = 16; off; off >>= 1) pc += __shfl_down(pc, off);
            if (tid == 0) atomicAdd(c + b * T_ + t, pc);
        }
        __syncthreads();
        if (tid == 0) atomicAdd(cD, 1);
    }
}

// out = enc_dot[b,l] + c[b,t] + bEff + eDot4[t,b]
__global__ void k_final(const float* __restrict__ encDot, const float* __restrict__ c,
                        const float* __restrict__ bEff, const float* __restrict__ eDot4,
                        float* __restrict__ out) {
    int idx = blockIdx.x * 256 + threadIdx.x;  // grid 192 -> 49152
    const int half = B_ * T_ * S_;
    int w = idx < half ? idx : idx - half;
    int b = w / (T_ * S_);
    int r = w % (T_ * S_);
    int t = r / S_, sidx = r % S_;
    int l = (idx < half) ? sidx : (S_ + sidx);
    out[idx] = encDot[b * L_ + l] + c[b * T_ + t] + bEff[0] + eDot4[t * 8 + b];
}

// ---------------------------------------------------------------------------
extern "C" void kernel_launch(void* const* d_in, const int* in_sizes, int n_in,
                              void* d_out, int out_size, void* d_ws, size_t ws_size,
                              hipStream_t stream) {
    const int* pre = (const int*)d_in[0];
    const int* post = (const int*)d_in[1];
    const int* trg = (const int*)d_in[2];
    const float* emb = (const float*)d_in[3];
    const float* WihPre = (const float*)d_in[4];
    const float* WhhPre = (const float*)d_in[5];
    const float* bihPre = (const float*)d_in[6];
    const float* bhhPre = (const float*)d_in[7];
    const float* WihPost = (const float*)d_in[8];
    const float* WhhPost = (const float*)d_in[9];
    const float* bihPost = (const float*)d_in[10];
    const float* bhhPost = (const float*)d_in[11];
    const float* fcEncW = (const float*)d_in[12];
    const float* fcEncB = (const float*)d_in[13];
    const float* attnW = (const float*)d_in[14];
    const float* attnB = (const float*)d_in[15];
    const float* attnV = (const float*)d_in[16];
    const float* WihDec = (const float*)d_in[17];
    const float* WhhDec = (const float*)d_in[18];
    const float* bihDec = (const float*)d_in[19];
    const float* bhhDec = (const float*)d_in[20];
    const float* fcHidW = (const float*)d_in[21];
    const float* fcHidB = (const float*)d_in[22];
    const float* fcOutW = (const float*)d_in[23];
    const float* fcOutB = (const float*)d_in[24];
    float* outp = (float*)d_out;

    float* base = (float*)d_ws;
    size_t off = 0;
    auto alloc = [&](size_t n) {
        float* p = base + off;
        off += (n + 63) & ~(size_t)63;
        return p;
    };
    float* giPre = alloc(1024 * 1536);
    float* giPost = alloc(1024 * 1536);
    float* giE = alloc(192 * 1536);
    float* encOut = alloc(8 * 256 * 512);
    float* encProj = alloc(8 * 256 * 512);
    float* wEff = alloc(2048);
    float* bEff = alloc(64);
    float* encDot = alloc(2048);
    float* eDot4 = alloc(256);
    float* hBuf = alloc(4096);
    float* cBuf = alloc(256);
    float* hboxPre = alloc(2 * 4096);
    float* hboxPost = alloc(2 * 4096);
    float* hpB = alloc(4096);
    float* scB = alloc(2048);
    float* wB = alloc(4096);
    float* hD = alloc(4096);
    int* encCnt = (int*)alloc(128);
    int* dcnt = (int*)alloc(2048);
    int* idxPre = (int*)alloc(1024);
    int* idxPost = (int*)alloc(1024);
    int* idxTok = (int*)alloc(256);

    k_init<<<8, 256, 0, stream>>>(pre, post, trg, idxPre, idxPost, idxTok, wEff, cBuf,
                                  encCnt, dcnt);
    k_weff<<<129, 256, 0, stream>>>(fcHidW, fcHidB, fcOutW, fcOutB, wEff, bEff);
    k_gemm<<<dim3(16, 24, 2), 256, 0, stream>>>(emb, idxPre, idxPost, 512,
                                                WihPre, WihPost, 512, bihPre, bihPost,
                                                giPre, giPost, 1536, 512);
    k_gemm<<<dim3(3, 24, 1), 256, 0, stream>>>(emb, idxTok, idxTok, 512,
                                               WihDec, WihDec, 1024, bihDec, bihDec,
                                               giE, giE, 1536, 512);
    k_encoder<<<64, 256, 0, stream>>>(giPre, giPost, WhhPre, WhhPost, bhhPre, bhhPost,
                                      encOut, hboxPre, hboxPost, encCnt);
    k_gemm<<<dim3(32, 8, 1), 256, 0, stream>>>(encOut, nullptr, nullptr, 512,
                                               attnW + 512, attnW + 512, 1024, attnB, attnB,
                                               encProj, encProj, 512, 512);
    k_fcenc<<<16, 256, 0, stream>>>(encOut, fcEncW, fcEncB, hBuf);
    k_encdot<<<32, 256, 0, stream>>>(encOut, wEff, encDot);
    k_edot4<<<192, 64, 0, stream>>>(emb, idxTok, wEff, eDot4);
    k_decoder<<<128, 128, 0, stream>>>(encOut, encProj, attnW, attnV, WihDec, WhhDec, bhhDec,
                                       giE, wEff, hBuf, hpB, scB, wB, hD, cBuf, dcnt);
    k_final<<<192, 256, 0, stream>>>(encDot, cBuf, bEff, eDot4, outp);
}